// Round 3
// baseline (557.022 us; speedup 1.0000x reference)
//
#include <hip/hip_runtime.h>
#include <math.h>

#define NROWS 65536
#define DDIM  64
#define KCB   1024

// ---------------------------------------------------------------------------
// Kernel 1: C2[j] = ||W_j||^2 via numpy pairwise-sum emulation (n=64: 8 accs).
// ---------------------------------------------------------------------------
__global__ void vq_c2_kernel(const float* __restrict__ W, float* __restrict__ C2) {
    int j = blockIdx.x * blockDim.x + threadIdx.x;
    if (j >= KCB) return;
    const float* w = W + (size_t)j * DDIM;
    float r[8];
#pragma unroll
    for (int m = 0; m < 8; ++m) r[m] = __fmul_rn(w[m], w[m]);
#pragma unroll
    for (int i = 8; i < 64; i += 8) {
#pragma unroll
        for (int m = 0; m < 8; ++m)
            r[m] = __fadd_rn(r[m], __fmul_rn(w[i + m], w[i + m]));
    }
    float res = __fadd_rn(
        __fadd_rn(__fadd_rn(r[0], r[1]), __fadd_rn(r[2], r[3])),
        __fadd_rn(__fadd_rn(r[4], r[5]), __fadd_rn(r[6], r[7])));
    C2[j] = res;
}

// ---------------------------------------------------------------------------
// Kernel 2: main argmin. Block = 256 threads = 4 waves, owns 16 ROWS.
// Lane decomposition: r = lane&15 -> row blockIdx*16+r; chunk = s*4+(lane>>4)
// -> codes [chunk*64, chunk*64+64). 4096 blocks = 16 blocks/CU, so the grid
// no longer caps occupancy (previous mapping: 1024 blocks = 16 waves/CU cap,
// observed 35% occupancy, ~60% of time stalled on wave-uniform W fetches).
// More resident waves -> scalar-load latency hidden across waves.
//
// Math is byte-identical to the 222us baseline: sequential fp32 FMA chain
// over k=0..63 per (row,code), dist = (L2 - 2*CL) + C2, L2 via numpy
// pairwise sum. First-index tie-break: strict < scanning ascending j within
// a chunk, then ascending-chunk strict-< combine.
// ---------------------------------------------------------------------------
__global__ void __launch_bounds__(256, 4)
vq_main_kernel(const float* __restrict__ x, const float* __restrict__ W,
               const float* __restrict__ C2, int* __restrict__ cls_i,
               float* __restrict__ cls_f) {
    __shared__ float s_bd[16][16];  // [chunk][row_in_block]
    __shared__ int   s_bi[16][16];

    const int lane  = threadIdx.x & 63;
    const int s     = __builtin_amdgcn_readfirstlane(threadIdx.x >> 6);
    const int r     = lane & 15;
    const int g     = lane >> 4;
    const int chunk = s * 4 + g;
    const int row   = blockIdx.x * 16 + r;

    // Load this row of x into registers (16 x float4). 4 lanes share a row;
    // the redundant loads hit the same L2 lines (broadcast), HBM fetch ~1x.
    const float* xr = x + (size_t)row * DDIM;
    float xv[64];
#pragma unroll
    for (int k = 0; k < 64; k += 4) {
        float4 v = *(const float4*)(xr + k);
        xv[k] = v.x; xv[k + 1] = v.y; xv[k + 2] = v.z; xv[k + 3] = v.w;
    }

    // L2 = numpy pairwise sum of x*x (n=64).
    float rr[8];
#pragma unroll
    for (int m = 0; m < 8; ++m) rr[m] = __fmul_rn(xv[m], xv[m]);
#pragma unroll
    for (int i = 8; i < 64; i += 8) {
#pragma unroll
        for (int m = 0; m < 8; ++m)
            rr[m] = __fadd_rn(rr[m], __fmul_rn(xv[i + m], xv[i + m]));
    }
    const float L2 = __fadd_rn(
        __fadd_rn(__fadd_rn(rr[0], rr[1]), __fadd_rn(rr[2], rr[3])),
        __fadd_rn(__fadd_rn(rr[4], rr[5]), __fadd_rn(rr[6], rr[7])));

    float best = INFINITY;
    int   bidx = 0;
    const int j0 = chunk * 64;
    for (int jj = 0; jj < 64; ++jj) {
        const int j = j0 + jj;
        const float* wr = W + (size_t)j * DDIM;
        float acc = 0.0f;
#pragma unroll
        for (int k = 0; k < 64; ++k)
            acc = __builtin_fmaf(xv[k], wr[k], acc);
        const float dist = __fadd_rn(__fsub_rn(L2, __fmul_rn(2.0f, acc)), C2[j]);
        if (dist < best) { best = dist; bidx = j; }  // strict <: keep lowest j
    }

    s_bd[chunk][r] = best;
    s_bi[chunk][r] = bidx;
    __syncthreads();

    // One thread per row combines 16 chunk-candidates in ascending-j order.
    if (threadIdx.x < 16) {
        const int rw = threadIdx.x;
        float b  = s_bd[0][rw];
        int   bi = s_bi[0][rw];
#pragma unroll
        for (int t = 1; t < 16; ++t) {
            const float d = s_bd[t][rw];
            if (d < b) { b = d; bi = s_bi[t][rw]; }  // ascending j-ranges
        }
        const int orow = blockIdx.x * 16 + rw;
        cls_i[orow] = bi;
        cls_f[orow] = (float)bi;  // harness reads indices as fp32
    }
}

// ---------------------------------------------------------------------------
// Kernel 3: gather quantized = W[closest]. 16 threads/row, float4 each.
// ---------------------------------------------------------------------------
__global__ void vq_gather_kernel(const float* __restrict__ W,
                                 const int* __restrict__ cls,
                                 float* __restrict__ outq) {
    const int t = blockIdx.x * blockDim.x + threadIdx.x;
    const int i = t >> 4;
    const int q = t & 15;
    const int j = cls[i];
    const float4 v = *(const float4*)(W + (size_t)j * DDIM + q * 4);
    *(float4*)(outq + (size_t)i * DDIM + q * 4) = v;
}

extern "C" void kernel_launch(void* const* d_in, const int* in_sizes, int n_in,
                              void* d_out, int out_size, void* d_ws, size_t ws_size,
                              hipStream_t stream) {
    const float* x = (const float*)d_in[0];
    const float* W = (const float*)d_in[1];

    float* outq = (float*)d_out;                        // N*D quantized
    float* outi = (float*)d_out + (size_t)NROWS * DDIM; // N indices as float

    float* C2  = (float*)d_ws;                          // 4 KB
    int*   cls = (int*)((char*)d_ws + 4096);            // 256 KB

    hipLaunchKernelGGL(vq_c2_kernel, dim3(KCB / 256), dim3(256), 0, stream, W, C2);
    hipLaunchKernelGGL(vq_main_kernel, dim3(NROWS / 16), dim3(256), 0, stream,
                       x, W, C2, cls, outi);
    hipLaunchKernelGGL(vq_gather_kernel, dim3((NROWS * 16) / 256), dim3(256), 0,
                       stream, W, cls, outq);
}

// Round 4
// 225.373 us; speedup vs baseline: 2.4716x; 2.4716x over previous
//
#include <hip/hip_runtime.h>
#include <math.h>

#define NROWS 65536
#define DDIM  64
#define KCB   1024

// ---------------------------------------------------------------------------
// Kernel 1: C2[j] = ||W_j||^2 via numpy pairwise-sum emulation (n=64: 8 accs).
// ---------------------------------------------------------------------------
__global__ void vq_c2_kernel(const float* __restrict__ W, float* __restrict__ C2) {
    int j = blockIdx.x * blockDim.x + threadIdx.x;
    if (j >= KCB) return;
    const float* w = W + (size_t)j * DDIM;
    float r[8];
#pragma unroll
    for (int m = 0; m < 8; ++m) r[m] = __fmul_rn(w[m], w[m]);
#pragma unroll
    for (int i = 8; i < 64; i += 8) {
#pragma unroll
        for (int m = 0; m < 8; ++m)
            r[m] = __fadd_rn(r[m], __fmul_rn(w[i + m], w[i + m]));
    }
    float res = __fadd_rn(
        __fadd_rn(__fadd_rn(r[0], r[1]), __fadd_rn(r[2], r[3])),
        __fadd_rn(__fadd_rn(r[4], r[5]), __fadd_rn(r[6], r[7])));
    C2[j] = res;
}

// ---------------------------------------------------------------------------
// Kernel 2: main argmin. Round-0 structure (the 222us-verified anchor):
// block = 256 threads = 4 waves; block owns 64 rows; lane l -> row
// blockIdx*64+l; wave s scans codes [s*256, s*256+256). ROUND-3 LESSON:
// W addressing must be wave-uniform (lane-dependent W pointers -> per-lane
// VMEM gather -> 3x regression).
//
// THIS ROUND'S CHANGE: W delivery via wave-uniform VECTOR loads (identical
// address across all 64 lanes -> one coalesced request, broadcast), software-
// pipelined: two 4xfloat4 buffers, chunk c+1 loads issued before chunk c's
// FMAs retire. Replaces the s_load path (96-SGPR budget forced ~4 serialized
// lgkmcnt(0) waits per j through a thrashing scalar cache). VMEM has deep
// vmcnt queuing and L1 backing; latency hides under FMAs + 16 waves/CU.
//
// Math byte-identical: CL = sequential fp32 FMA chain k=0..63, dist =
// (L2 - 2*CL) + C2, L2 pairwise. Strict-< ascending-j tie-break.
// ---------------------------------------------------------------------------
__global__ void __launch_bounds__(256, 4)
vq_main_kernel(const float* __restrict__ x, const float* __restrict__ W,
               const float* __restrict__ C2, int* __restrict__ cls_i,
               float* __restrict__ cls_f) {
    __shared__ float s_bd[4][64];
    __shared__ int   s_bi[4][64];

    const int lane = threadIdx.x & 63;
    const int s    = __builtin_amdgcn_readfirstlane(threadIdx.x >> 6);
    const int row  = blockIdx.x * 64 + lane;

    // Load this row of x into registers (16 x float4).
    const float* xr = x + (size_t)row * DDIM;
    float xv[64];
#pragma unroll
    for (int k = 0; k < 64; k += 4) {
        float4 v = *(const float4*)(xr + k);
        xv[k] = v.x; xv[k + 1] = v.y; xv[k + 2] = v.z; xv[k + 3] = v.w;
    }

    // L2 = numpy pairwise sum of x*x (n=64).
    float r[8];
#pragma unroll
    for (int m = 0; m < 8; ++m) r[m] = __fmul_rn(xv[m], xv[m]);
#pragma unroll
    for (int i = 8; i < 64; i += 8) {
#pragma unroll
        for (int m = 0; m < 8; ++m)
            r[m] = __fadd_rn(r[m], __fmul_rn(xv[i + m], xv[i + m]));
    }
    const float L2 = __fadd_rn(
        __fadd_rn(__fadd_rn(r[0], r[1]), __fadd_rn(r[2], r[3])),
        __fadd_rn(__fadd_rn(r[4], r[5]), __fadd_rn(r[6], r[7])));

    float best = INFINITY;
    int   bidx = 0;
    const int j0 = s * 256;
    // Wave-uniform float4 view of this wave's W slice (16 float4 per row).
    const float4* wq = (const float4*)(W + (size_t)j0 * DDIM);

    // FMA chunk c (floats 4a..4a+15 of row jj) in exact sequential k-order.
#define VQ_CHAIN4(B, A)                                                   \
    do {                                                                  \
        acc = __builtin_fmaf(xv[(A) * 4 + 0], (B)[0].x, acc);             \
        acc = __builtin_fmaf(xv[(A) * 4 + 1], (B)[0].y, acc);             \
        acc = __builtin_fmaf(xv[(A) * 4 + 2], (B)[0].z, acc);             \
        acc = __builtin_fmaf(xv[(A) * 4 + 3], (B)[0].w, acc);             \
        acc = __builtin_fmaf(xv[(A) * 4 + 4], (B)[1].x, acc);             \
        acc = __builtin_fmaf(xv[(A) * 4 + 5], (B)[1].y, acc);             \
        acc = __builtin_fmaf(xv[(A) * 4 + 6], (B)[1].z, acc);             \
        acc = __builtin_fmaf(xv[(A) * 4 + 7], (B)[1].w, acc);             \
        acc = __builtin_fmaf(xv[(A) * 4 + 8], (B)[2].x, acc);             \
        acc = __builtin_fmaf(xv[(A) * 4 + 9], (B)[2].y, acc);             \
        acc = __builtin_fmaf(xv[(A) * 4 + 10], (B)[2].z, acc);            \
        acc = __builtin_fmaf(xv[(A) * 4 + 11], (B)[2].w, acc);            \
        acc = __builtin_fmaf(xv[(A) * 4 + 12], (B)[3].x, acc);            \
        acc = __builtin_fmaf(xv[(A) * 4 + 13], (B)[3].y, acc);            \
        acc = __builtin_fmaf(xv[(A) * 4 + 14], (B)[3].z, acc);            \
        acc = __builtin_fmaf(xv[(A) * 4 + 15], (B)[3].w, acc);            \
    } while (0)

    float4 bufA[4], bufB[4];
    // Prologue: row 0, chunk 0 -> bufA.
#pragma unroll
    for (int q = 0; q < 4; ++q) bufA[q] = wq[q];

#pragma unroll 1  // keep the body ~100 instr: I$-resident, rolled
    for (int jj = 0; jj < 256; ++jj) {
        const int base = jj * 16;
        float acc = 0.0f;
        // c=0: prefetch chunk1 -> bufB, FMA chunk0 from bufA.
#pragma unroll
        for (int q = 0; q < 4; ++q) bufB[q] = wq[base + 4 + q];
        VQ_CHAIN4(bufA, 0);
        // c=1: prefetch chunk2 -> bufA, FMA chunk1 from bufB.
#pragma unroll
        for (int q = 0; q < 4; ++q) bufA[q] = wq[base + 8 + q];
        VQ_CHAIN4(bufB, 4);
        // c=2: prefetch chunk3 -> bufB, FMA chunk2 from bufA.
#pragma unroll
        for (int q = 0; q < 4; ++q) bufB[q] = wq[base + 12 + q];
        VQ_CHAIN4(bufA, 8);
        // c=3: prefetch next row chunk0 -> bufA ((jj+1)&255: harmless wrap
        // on the last iteration, stays inside this wave's slice), FMA chunk3.
        const int nbase = ((jj + 1) & 255) * 16;
#pragma unroll
        for (int q = 0; q < 4; ++q) bufA[q] = wq[nbase + q];
        VQ_CHAIN4(bufB, 12);

        const float dist = __fadd_rn(__fsub_rn(L2, __fmul_rn(2.0f, acc)), C2[j0 + jj]);
        if (dist < best) { best = dist; bidx = j0 + jj; }  // strict <: lowest j
    }
#undef VQ_CHAIN4

    s_bd[s][lane] = best;
    s_bi[s][lane] = bidx;
    __syncthreads();

    if (s == 0) {
        float b  = s_bd[0][lane];
        int   bi = s_bi[0][lane];
#pragma unroll
        for (int t = 1; t < 4; ++t) {
            const float d = s_bd[t][lane];
            if (d < b) { b = d; bi = s_bi[t][lane]; }  // ascending j-ranges
        }
        cls_i[row] = bi;
        cls_f[row] = (float)bi;  // harness reads indices as fp32
    }
}

// ---------------------------------------------------------------------------
// Kernel 3: gather quantized = W[closest]. 16 threads/row, float4 each.
// ---------------------------------------------------------------------------
__global__ void vq_gather_kernel(const float* __restrict__ W,
                                 const int* __restrict__ cls,
                                 float* __restrict__ outq) {
    const int t = blockIdx.x * blockDim.x + threadIdx.x;
    const int i = t >> 4;
    const int q = t & 15;
    const int j = cls[i];
    const float4 v = *(const float4*)(W + (size_t)j * DDIM + q * 4);
    *(float4*)(outq + (size_t)i * DDIM + q * 4) = v;
}

extern "C" void kernel_launch(void* const* d_in, const int* in_sizes, int n_in,
                              void* d_out, int out_size, void* d_ws, size_t ws_size,
                              hipStream_t stream) {
    const float* x = (const float*)d_in[0];
    const float* W = (const float*)d_in[1];

    float* outq = (float*)d_out;                        // N*D quantized
    float* outi = (float*)d_out + (size_t)NROWS * DDIM; // N indices as float

    float* C2  = (float*)d_ws;                          // 4 KB
    int*   cls = (int*)((char*)d_ws + 4096);            // 256 KB

    hipLaunchKernelGGL(vq_c2_kernel, dim3(KCB / 256), dim3(256), 0, stream, W, C2);
    hipLaunchKernelGGL(vq_main_kernel, dim3(NROWS / 64), dim3(256), 0, stream,
                       x, W, C2, cls, outi);
    hipLaunchKernelGGL(vq_gather_kernel, dim3((NROWS * 16) / 256), dim3(256), 0,
                       stream, W, cls, outq);
}